// Round 1
// 347.471 us; speedup vs baseline: 1.0220x; 1.0220x over previous
//
#include <hip/hip_runtime.h>

// LengthRegulator: B=64, S=1024, D=512, T=2048 (fixed by setup_inputs)
// Single fused kernel: each block recomputes the durations prefix-scan for its
// batch (cheap, ~100 cycles + one 4 KB L2-resident load), scatter-fills the
// 64 frame ids it needs, then does the register-blocked streaming gather-copy.
// This removes the separate scan kernel, the device-wide kernel boundary, and
// the fidx workspace round-trip.
constexpr int B = 64;
constexpr int S = 1024;
constexpr int D = 512;
constexpr int T = 2048;
constexpr int FPB = 64;            // frames per block
constexpr int CHUNKS = T / FPB;    // 32

typedef float floatx4 __attribute__((ext_vector_type(4)));

__global__ __launch_bounds__(256) void lr_fused_kernel(
    const float* __restrict__ x,     // [B, S, D]
    const int*   __restrict__ dur,   // [B, S]
    float*       __restrict__ out,   // [B, T, D]
    float*       __restrict__ mask)  // [B, T]
{
    __shared__ int fr[FPB];          // source frame id per output frame, -1 => masked
    __shared__ int wave_tot[4];

    const int tid   = threadIdx.x;
    const int chunk = blockIdx.x;
    const int b     = blockIdx.y;
    const int t0    = chunk * FPB;
    const int t1    = t0 + FPB;
    const int lane  = tid & 63;
    const int wv    = tid >> 6;

    if (tid < FPB) fr[tid] = -1;     // slots past len stay -1

    // ---- per-block prefix scan of this batch's durations (4 elems/thread) ----
    const int4 d4 = ((const int4*)(dur + b * S))[tid];
    const int p0 = d4.x;
    const int p1 = p0 + d4.y;
    const int p2 = p1 + d4.z;
    const int p3 = p2 + d4.w;

    int incl = p3;
    #pragma unroll
    for (int off = 1; off < 64; off <<= 1) {
        const int v = __shfl_up(incl, off, 64);
        if (lane >= off) incl += v;
    }
    if (lane == 63) wave_tot[wv] = incl;
    __syncthreads();

    int woff = 0;
    #pragma unroll
    for (int w = 0; w < 4; ++w) woff += (w < wv) ? wave_tot[w] : 0;
    const int excl = woff + incl - p3;           // exclusive prefix of frame 4*tid

    // ---- scatter-fill: frame s covers output span [start_s, end_s) ----------
    // Spans partition [0, len), so each fr slot is written by exactly one thread.
    const int s0 = 4 * tid;
    const int st0 = excl;
    const int st1 = excl + p0;
    const int st2 = excl + p1;
    const int st3 = excl + p2;
    const int st4 = excl + p3;
    #pragma unroll
    for (int j = 0; j < 4; ++j) {
        const int a0 = (j == 0) ? st0 : (j == 1) ? st1 : (j == 2) ? st2 : st3;
        const int e0 = (j == 0) ? st1 : (j == 1) ? st2 : (j == 2) ? st3 : st4;
        int a = a0 < t0 ? t0 : a0;
        const int e = e0 > t1 ? t1 : e0;
        for (int t = a; t < e; ++t) fr[t - t0] = s0 + j;   // <=7 iters, few active lanes
    }
    __syncthreads();

    if (tid < FPB)
        mask[(size_t)b * T + t0 + tid] = (fr[tid] < 0) ? 1.0f : 0.0f;

    // ---- streaming gather-copy: one wave owns 16 consecutive frames ---------
    const floatx4* xb = (const floatx4*)(x + (size_t)b * S * D);
    floatx4*       ob = (floatx4*)(out + ((size_t)b * T + t0) * D)
                        + (size_t)(wv * 16) * (D / 4);

    // hoist all 16 frame ids into scalar regs (one batched LDS wait)
    int sid[16];
    #pragma unroll
    for (int k = 0; k < 16; ++k)
        sid[k] = __builtin_amdgcn_readfirstlane(fr[wv * 16 + k]);

    #pragma unroll
    for (int batch = 0; batch < 2; ++batch) {
        floatx4 v[8][2];
        #pragma unroll
        for (int f = 0; f < 8; ++f) {
            const int id = sid[batch * 8 + f];
            v[f][0] = (floatx4)(0.f);
            v[f][1] = (floatx4)(0.f);
            if (id >= 0) {           // scalar (wave-uniform) branch
                const floatx4* src = xb + (size_t)id * (D / 4);
                v[f][0] = src[lane];
                v[f][1] = src[lane + 64];
            }
        }
        #pragma unroll
        for (int f = 0; f < 8; ++f) {
            floatx4* dst = ob + (size_t)(batch * 8 + f) * (D / 4);
            __builtin_nontemporal_store(v[f][0], dst + lane);
            __builtin_nontemporal_store(v[f][1], dst + lane + 64);
        }
    }
}

extern "C" void kernel_launch(void* const* d_in, const int* in_sizes, int n_in,
                              void* d_out, int out_size, void* d_ws, size_t ws_size,
                              hipStream_t stream) {
    const float* x   = (const float*)d_in[0];
    const int*   dur = (const int*)d_in[1];
    float* out  = (float*)d_out;
    float* mask = out + (size_t)B * T * D;   // outputs concatenated flat

    dim3 grid(CHUNKS, B);
    lr_fused_kernel<<<grid, 256, 0, stream>>>(x, dur, out, mask);
}